// Round 5
// baseline (79.002 us; speedup 1.0000x reference)
//
#include <hip/hip_runtime.h>
#include <float.h>

#define NT 4096
#define EMB 8

typedef unsigned long long u64;
typedef unsigned int u32;

// lexicographic (d, j) strict less-than: smaller distance first, ties -> smaller j
#define LEXLT(da, ja, db, jb) (((da) < (db)) || (((da) == (db)) && ((ja) < (jb))))

// compare-exchange on (d,j) pairs: after this, (dx,jx) <= (dy,jy) lexicographically
#define CESWAP(dx, jx, dy, jy) do {                                   \
    const bool t_ = LEXLT(dy, jy, dx, jx);                            \
    const float td_ = t_ ? dy : dx;  const int tj_ = t_ ? jy : jx;    \
    dy = t_ ? dx : dy;  jy = t_ ? jx : jy;                            \
    dx = td_;           jx = tj_;                                     \
} while (0)

__device__ __forceinline__ u64 shfl_xor_u64(u64 v, int off) {
    const int lo = __shfl_xor((int)(v & 0xFFFFFFFFull), off, 64);
    const int hi = __shfl_xor((int)(v >> 32), off, 64);
    return ((u64)(u32)hi << 32) | (u32)lo;
}

__global__ __launch_bounds__(256) void nn_pool_kernel(
    const float* __restrict__ obs1,
    const float* __restrict__ obs2,
    const float* __restrict__ W,
    const float* __restrict__ bias,
    float* __restrict__ out)       // reference output dtype is FLOAT32
{
    __shared__ u64 s_top[4][4];    // 128 B: per-wave top-4 keys for pair merge

    const int tid  = threadIdx.x;
    const int w    = tid >> 6;            // wave in block (0..3)
    const int lane = tid & 63;
    const int row  = (blockIdx.x << 1) + (w >> 1);   // 2 rows per block
    const int h    = w & 1;                          // candidate half (0/1)

    const float2 pi = reinterpret_cast<const float2*>(obs2)[row];

    // Dual per-lane sorted top-4 lists (A = even j, B = odd j) over this
    // wave's 2048-candidate half. Distance = sqrt(dx*dx+dy*dy) with each op
    // individually rounded f32 (matches numpy bit-for-bit; no FMA contraction).
    float dA0=FLT_MAX,dA1=FLT_MAX,dA2=FLT_MAX,dA3=FLT_MAX;
    float dB0=FLT_MAX,dB1=FLT_MAX,dB2=FLT_MAX,dB3=FLT_MAX;
    int   jA0=0x7fffffff,jA1=0x7fffffff,jA2=0x7fffffff,jA3=0x7fffffff;
    int   jB0=0x7fffffff,jB1=0x7fffffff,jB2=0x7fffffff,jB3=0x7fffffff;

    const float4* pos4 = reinterpret_cast<const float4*>(obs2);
    const int fbase = (h << 10) + lane;   // float4 index: 2 points per load

    #pragma unroll 4
    for (int k = 0; k < 16; ++k) {
        const float4 v = pos4[fbase + (k << 6)];
        const int j0 = (h << 11) + (k << 7) + (lane << 1);
        const int j1 = j0 + 1;
        {
            const float dx = __fsub_rn(v.x, pi.x);
            const float dy = __fsub_rn(v.y, pi.y);
            float d = __fsqrt_rn(__fadd_rn(__fmul_rn(dx,dx), __fmul_rn(dy,dy)));
            if (j0 == row) d = FLT_MAX;
            const bool c3 = d < dA3, c2 = d < dA2, c1 = d < dA1, c0 = d < dA0;
            dA3 = c3 ? (c2 ? dA2 : d) : dA3;   jA3 = c3 ? (c2 ? jA2 : j0) : jA3;
            dA2 = c2 ? (c1 ? dA1 : d) : dA2;   jA2 = c2 ? (c1 ? jA1 : j0) : jA2;
            dA1 = c1 ? (c0 ? dA0 : d) : dA1;   jA1 = c1 ? (c0 ? jA0 : j0) : jA1;
            dA0 = c0 ? d : dA0;                jA0 = c0 ? j0 : jA0;
        }
        {
            const float dx = __fsub_rn(v.z, pi.x);
            const float dy = __fsub_rn(v.w, pi.y);
            float d = __fsqrt_rn(__fadd_rn(__fmul_rn(dx,dx), __fmul_rn(dy,dy)));
            if (j1 == row) d = FLT_MAX;
            const bool c3 = d < dB3, c2 = d < dB2, c1 = d < dB1, c0 = d < dB0;
            dB3 = c3 ? (c2 ? dB2 : d) : dB3;   jB3 = c3 ? (c2 ? jB2 : j1) : jB3;
            dB2 = c2 ? (c1 ? dB1 : d) : dB2;   jB2 = c2 ? (c1 ? jB1 : j1) : jB2;
            dB1 = c1 ? (c0 ? dB0 : d) : dB1;   jB1 = c1 ? (c0 ? jB0 : j1) : jB1;
            dB0 = c0 ? d : dB0;                jB0 = c0 ? j1 : jB0;
        }
    }

    // in-lane bitonic merge of sorted A and sorted B -> sorted top-4
    float l0, l1, l2, l3; int m0, m1, m2, m3;
    { const bool t = LEXLT(dB3,jB3,dA0,jA0); l0 = t?dB3:dA0; m0 = t?jB3:jA0; }
    { const bool t = LEXLT(dB2,jB2,dA1,jA1); l1 = t?dB2:dA1; m1 = t?jB2:jA1; }
    { const bool t = LEXLT(dB1,jB1,dA2,jA2); l2 = t?dB1:dA2; m2 = t?jB1:jA2; }
    { const bool t = LEXLT(dB0,jB0,dA3,jA3); l3 = t?dB0:dA3; m3 = t?jB0:jA3; }
    CESWAP(l0,m0,l2,m2); CESWAP(l1,m1,l3,m3); CESWAP(l0,m0,l1,m1); CESWAP(l2,m2,l3,m3);

    // pack (d, j) -> u64 key; d >= 0 so f32 bits order monotonically
    u64 k0 = ((u64)__float_as_uint(l0) << 32) | (u32)m0;
    u64 k1 = ((u64)__float_as_uint(l1) << 32) | (u32)m1;
    u64 k2 = ((u64)__float_as_uint(l2) << 32) | (u32)m2;
    u64 k3 = ((u64)__float_as_uint(l3) << 32) | (u32)m3;

    // 6-step butterfly: merge two sorted 4-lists per step (bitonic)
    #pragma unroll
    for (int off = 1; off < 64; off <<= 1) {
        const u64 p0 = shfl_xor_u64(k0, off);
        const u64 p1 = shfl_xor_u64(k1, off);
        const u64 p2 = shfl_xor_u64(k2, off);
        const u64 p3 = shfl_xor_u64(k3, off);
        u64 a0 = k0 < p3 ? k0 : p3;
        u64 a1 = k1 < p2 ? k1 : p2;
        u64 a2 = k2 < p1 ? k2 : p1;
        u64 a3 = k3 < p0 ? k3 : p0;
        { const u64 t = a0 < a2 ? a0 : a2; a2 = a0 < a2 ? a2 : a0; a0 = t; }
        { const u64 t = a1 < a3 ? a1 : a3; a3 = a1 < a3 ? a3 : a1; a1 = t; }
        { const u64 t = a0 < a1 ? a0 : a1; a1 = a0 < a1 ? a1 : a0; a0 = t; }
        { const u64 t = a2 < a3 ? a2 : a3; a3 = a2 < a3 ? a3 : a2; a2 = t; }
        k0 = a0; k1 = a1; k2 = a2; k3 = a3;
    }

    // cross-wave pair merge (the two half-scans of this row) via tiny LDS
    if (lane < 4)
        s_top[w][lane] = (lane == 0) ? k0 : (lane == 1) ? k1 : (lane == 2) ? k2 : k3;
    __syncthreads();

    const int pw = w ^ 1;
    const u64 q0 = s_top[pw][0], q1 = s_top[pw][1], q2 = s_top[pw][2], q3 = s_top[pw][3];
    u64 a0 = k0 < q3 ? k0 : q3;
    u64 a1 = k1 < q2 ? k1 : q2;
    u64 a2 = k2 < q1 ? k2 : q1;
    u64 a3 = k3 < q0 ? k3 : q0;
    { const u64 t = a0 < a2 ? a0 : a2; a2 = a0 < a2 ? a2 : a0; a0 = t; }
    { const u64 t = a1 < a3 ? a1 : a3; a3 = a1 < a3 ? a3 : a1; a1 = t; }
    { const u64 t = a0 < a1 ? a0 : a1; a1 = a0 < a1 ? a1 : a0; a0 = t; }
    { const u64 t = a2 < a3 ? a2 : a3; a3 = a2 < a3 ? a3 : a2; a2 = t; }

    // h==0 wave of each row emits: lane = t*8 + e -> out[row, t*EMB + e]
    if (h == 0 && lane < 32) {
        const int t = lane >> 3;
        const int e = lane & 7;
        const u64 key = (t == 0) ? a0 : (t == 1) ? a1 : (t == 2) ? a2 : a3;
        const int j = (int)((u32)key) & (NT - 1);   // low 32 bits = index

        const float2* g_pos = reinterpret_cast<const float2*>(obs2);
        const float2* g_o1  = reinterpret_cast<const float2*>(obs1);
        const float2 pj  = g_pos[j];
        const float2 o1j = g_o1[j];
        const float2 o1i = g_o1[row];

        const float dx  = pj.x - pi.x;
        const float dy  = pj.y - pi.y;
        const float dvx = (pj.x - o1j.x) - (pi.x - o1i.x);
        const float dvy = (pj.y - o1j.y) - (pi.y - o1i.y);

        float acc = bias[e]
                  + dx  * W[0 * EMB + e]
                  + dy  * W[1 * EMB + e]
                  + dvx * W[2 * EMB + e]
                  + dvy * W[3 * EMB + e];
        out[row * 32 + lane] = fmaxf(acc, 0.0f);
    }
}

extern "C" void kernel_launch(void* const* d_in, const int* in_sizes, int n_in,
                              void* d_out, int out_size, void* d_ws, size_t ws_size,
                              hipStream_t stream) {
    // Resolve inputs BY SIZE (defensive; falls back to dict order).
    const float* obs1 = nullptr;
    const float* obs2 = nullptr;
    const float* W    = nullptr;
    const float* bias = nullptr;
    int big_seen = 0;
    for (int i = 0; i < n_in; ++i) {
        if (in_sizes[i] == 2 * NT) {
            if (big_seen++ == 0) obs1 = (const float*)d_in[i];
            else                 obs2 = (const float*)d_in[i];
        } else if (in_sizes[i] == 4 * EMB) {
            W = (const float*)d_in[i];
        } else if (in_sizes[i] == EMB) {
            bias = (const float*)d_in[i];
        }
    }
    if (!obs1 || !obs2 || !W || !bias) {
        obs1 = (const float*)d_in[0];
        obs2 = (const float*)d_in[1];
        W    = (const float*)d_in[2];
        bias = (const float*)d_in[3];
    }
    float* out = (float*)d_out;

    nn_pool_kernel<<<NT / 2, 256, 0, stream>>>(obs1, obs2, W, bias, out);
}